// Round 1
// baseline (395.313 us; speedup 1.0000x reference)
//
#include <hip/hip_runtime.h>

// AttentionLayer: B=16, T=S=C=E=1024, NORM_C=0.5
// out  = (ctx @ w_out^T + b_out + x) * sqrt(.5)   [f32, first 16M elems of d_out]
// attn = softmax(mask(h @ K))                     [f32, next 16M elems]
// h = (x @ w_in^T + b_in + te) * sqrt(.5); ctx = (attn @ V) * sqrt(S - sum(mask))
// Strategy: fp16 MFMA (16x16x32) for all 4 GEMMs, f32 accumulate, f32 softmax.

#define SCALE_F 0.70710678118654752440f

constexpr int BB = 16, TT = 1024, SS = 1024, CC = 1024, EE = 1024;

typedef float    f32x4 __attribute__((ext_vector_type(4)));
typedef _Float16 f16x8 __attribute__((ext_vector_type(8)));
typedef _Float16 f16x4 __attribute__((ext_vector_type(4)));

__device__ __forceinline__ void gload_lds16(const _Float16* g, _Float16* l) {
  __builtin_amdgcn_global_load_lds((const __attribute__((address_space(1))) void*)g,
                                   (__attribute__((address_space(3))) void*)l,
                                   16, 0, 0);
}

// ---------------------------------------------------------------- conversions
__global__ __launch_bounds__(256) void cvt_f16(const float* __restrict__ s,
                                               _Float16* __restrict__ d, long n) {
  long i = ((long)blockIdx.x * 256 + threadIdx.x) * 8;
  if (i >= n) return;
  f32x4 a = *(const f32x4*)(s + i);
  f32x4 b = *(const f32x4*)(s + i + 4);
  f16x8 h;
  h[0]=(_Float16)a[0]; h[1]=(_Float16)a[1]; h[2]=(_Float16)a[2]; h[3]=(_Float16)a[3];
  h[4]=(_Float16)b[0]; h[5]=(_Float16)b[1]; h[6]=(_Float16)b[2]; h[7]=(_Float16)b[3];
  *(f16x8*)(d + i) = h;
}

// src: [B][R][Cc] f32  ->  dst: [B][Cc][R] f16   (64x64 LDS tile transpose)
__global__ __launch_bounds__(256) void transpose_cvt(const float* __restrict__ src,
                                                     _Float16* __restrict__ dst,
                                                     int R, int Cc) {
  __shared__ float tile[64][65];
  const int b = blockIdx.z;
  const int r0 = blockIdx.y * 64, c0 = blockIdx.x * 64;
  const int t = threadIdx.x;
  const int tr = t >> 4, tc4 = (t & 15) * 4;
  const float* s = src + (size_t)b * R * Cc;
#pragma unroll
  for (int i = 0; i < 4; ++i) {
    f32x4 v = *(const f32x4*)(s + (size_t)(r0 + i * 16 + tr) * Cc + c0 + tc4);
    tile[i * 16 + tr][tc4 + 0] = v[0]; tile[i * 16 + tr][tc4 + 1] = v[1];
    tile[i * 16 + tr][tc4 + 2] = v[2]; tile[i * 16 + tr][tc4 + 3] = v[3];
  }
  __syncthreads();
  _Float16* d = dst + (size_t)b * Cc * R;
#pragma unroll
  for (int j = 0; j < 4; ++j) {
    const int cl = j * 16 + tr;  // dst row (source column)
    f16x4 h;
    h[0] = (_Float16)tile[tc4 + 0][cl]; h[1] = (_Float16)tile[tc4 + 1][cl];
    h[2] = (_Float16)tile[tc4 + 2][cl]; h[3] = (_Float16)tile[tc4 + 3][cl];
    *(f16x4*)(d + (size_t)(c0 + cl) * R + r0 + tc4) = h;
  }
}

// ------------------------------------------------------------------- mask prep
// Bool mask ABI is ambiguous (u8 vs i32 vs f32). Sniff the dword patterns:
// i32 mode -> dwords in {0,1}; f32 mode -> {0, 0x3f800000}; u8 mode -> other.
// Read path "u32 != 0" covers both i32 and f32; u8 path for byte mode.
__global__ __launch_bounds__(256) void mask_prep(const unsigned char* __restrict__ mraw,
                                                 float* __restrict__ maskneg,
                                                 float* __restrict__ sscale) {
  const int b = blockIdx.x, t = threadIdx.x;
  __shared__ int bytemode_sh, cnt_sh;
  if (t == 0) { bytemode_sh = 0; cnt_sh = 0; }
  __syncthreads();
  const unsigned int* mu = (const unsigned int*)mraw;
  int local = 0;
  for (int i = t; i < (BB * SS) / 4; i += 256) {   // 4096 dwords, safe in all modes
    unsigned int v = mu[i];
    if (v != 0u && v != 1u && v != 0x3f800000u) local = 1;
  }
  if (local) atomicOr(&bytemode_sh, 1);
  __syncthreads();
  const int bytemode = bytemode_sh;
  int cnt = 0;
  for (int s = t; s < SS; s += 256) {
    int m = bytemode ? (mraw[b * SS + s] != 0) : (mu[b * SS + s] != 0u);
    maskneg[b * SS + s] = m ? -__builtin_inff() : 0.0f;
    cnt += m;
  }
#pragma unroll
  for (int o = 32; o; o >>= 1) cnt += __shfl_down(cnt, o);
  if ((t & 63) == 0) atomicAdd(&cnt_sh, cnt);
  __syncthreads();
  if (t == 0) {
    float sv = (float)SS - (float)cnt_sh;
    sscale[b] = sv * rsqrtf(sv);   // matches s * rsqrt(s)
  }
}

// ---------------------------------------------------------------------- GEMM
// C[M,N] = A[M,K] @ Bmat[N,K]^T ; all operands fp16 K-major, f32 accum.
// 128x128 tile, BK=64, 256 thr (4 waves, 2x2), global_load_lds width 16.
// EPI 1: h16 = (acc + bias[n] + addmat[row,n]) * SCALE       (fp16 out)
// EPI 2: scores = acc + maskneg[z,n]                          (f32 out)
// EPI 3: ctx16 = acc * sscale[z]                              (fp16 out)
// EPI 4: out = (acc + bias[n] + addmat[row,n]) * SCALE        (f32 out)
template <int EPI>
__global__ __launch_bounds__(256)
void gemm_nt(const _Float16* __restrict__ A, const _Float16* __restrict__ Bmat,
             long aStride, long bStride, long oStride,
             int M, int N, int K,
             void* __restrict__ outp,
             const float* __restrict__ bias,
             const float* __restrict__ addmat,
             const float* __restrict__ extra) {
  constexpr int BM = 128, BN = 128, BK = 64;
  __shared__ _Float16 As[BM * BK];
  __shared__ _Float16 Bs[BN * BK];

  const int t = threadIdx.x;
  const int lane = t & 63;
  const int wid = t >> 6;
  const int wr = wid >> 1, wc = wid & 1;
  const int z = blockIdx.z;

  const long rowBase = (long)blockIdx.y * BM;
  const long colBase = (long)blockIdx.x * BN;

  const _Float16* Ag = A + (size_t)z * aStride + rowBase * K;
  const _Float16* Bg = Bmat + (size_t)z * bStride + colBase * K;

  const int srow = t >> 3;          // 0..31
  const int scol = (t & 7) * 8;     // 0..56

  f32x4 acc[4][4] = {};

  for (int k0 = 0; k0 < K; k0 += BK) {
#pragma unroll
    for (int q = 0; q < 4; ++q)
      gload_lds16(Ag + (size_t)(q * 32 + srow) * K + k0 + scol, &As[(q * 256 + t) * 8]);
#pragma unroll
    for (int q = 0; q < 4; ++q)
      gload_lds16(Bg + (size_t)(q * 32 + srow) * K + k0 + scol, &Bs[(q * 256 + t) * 8]);
    asm volatile("s_waitcnt vmcnt(0)" ::: "memory");
    __syncthreads();
#pragma unroll
    for (int ks = 0; ks < 2; ++ks) {
      f16x8 a[4], b[4];
#pragma unroll
      for (int m = 0; m < 4; ++m)
        a[m] = *(const f16x8*)&As[(wr * 64 + m * 16 + (lane & 15)) * BK + ks * 32 + (lane >> 4) * 8];
#pragma unroll
      for (int n = 0; n < 4; ++n)
        b[n] = *(const f16x8*)&Bs[(wc * 64 + n * 16 + (lane & 15)) * BK + ks * 32 + (lane >> 4) * 8];
#pragma unroll
      for (int m = 0; m < 4; ++m)
#pragma unroll
        for (int n = 0; n < 4; ++n)
          acc[m][n] = __builtin_amdgcn_mfma_f32_16x16x32_f16(a[m], b[n], acc[m][n], 0, 0, 0);
    }
    __syncthreads();
  }

  // C/D layout (m89-verified): col = lane&15, row = (lane>>4)*4 + j
  const int fr = lane & 15;
  const int fq = (lane >> 4) * 4;
#pragma unroll
  for (int m = 0; m < 4; ++m) {
#pragma unroll
    for (int n = 0; n < 4; ++n) {
      const long gc = colBase + wc * 64 + n * 16 + fr;
#pragma unroll
      for (int j = 0; j < 4; ++j) {
        const long gr = rowBase + wr * 64 + m * 16 + fq + j;
        const float v = acc[m][n][j];
        if constexpr (EPI == 1) {
          float r = (v + bias[gc] + addmat[gr * N + gc]) * SCALE_F;
          ((_Float16*)outp)[gr * N + gc] = (_Float16)r;
        } else if constexpr (EPI == 2) {
          ((float*)outp)[(size_t)z * oStride + gr * N + gc] = v + extra[(size_t)z * N + gc];
        } else if constexpr (EPI == 3) {
          ((_Float16*)outp)[(size_t)z * oStride + gr * N + gc] = (_Float16)(v * extra[z]);
        } else {
          ((float*)outp)[gr * N + gc] = (v + bias[gc] + addmat[gr * N + gc]) * SCALE_F;
        }
      }
    }
  }
}

// -------------------------------------------------------------------- softmax
// One block per row; 1024 f32 in-place + fp16 copy for the PV GEMM.
__global__ __launch_bounds__(256) void softmax_k(float* __restrict__ attn,
                                                 _Float16* __restrict__ attn16) {
  const size_t row = blockIdx.x;
  float* p = attn + row * SS;
  const int t = threadIdx.x;
  f32x4 v = *(const f32x4*)(p + t * 4);
  __shared__ float red[8];
  float m = fmaxf(fmaxf(v[0], v[1]), fmaxf(v[2], v[3]));
#pragma unroll
  for (int o = 32; o; o >>= 1) m = fmaxf(m, __shfl_xor(m, o));
  if (!(t & 63)) red[t >> 6] = m;
  __syncthreads();
  m = fmaxf(fmaxf(red[0], red[1]), fmaxf(red[2], red[3]));
  f32x4 e;
  e[0] = __expf(v[0] - m); e[1] = __expf(v[1] - m);
  e[2] = __expf(v[2] - m); e[3] = __expf(v[3] - m);
  float s = e[0] + e[1] + e[2] + e[3];
#pragma unroll
  for (int o = 32; o; o >>= 1) s += __shfl_xor(s, o);
  if (!(t & 63)) red[4 + (t >> 6)] = s;
  __syncthreads();
  s = red[4] + red[5] + red[6] + red[7];
  const float inv = 1.0f / s;
  f32x4 o4; o4[0]=e[0]*inv; o4[1]=e[1]*inv; o4[2]=e[2]*inv; o4[3]=e[3]*inv;
  *(f32x4*)(p + t * 4) = o4;
  f16x4 h; h[0]=(_Float16)o4[0]; h[1]=(_Float16)o4[1];
  h[2]=(_Float16)o4[2]; h[3]=(_Float16)o4[3];
  *(f16x4*)(attn16 + row * SS + t * 4) = h;
}

// -------------------------------------------------------------------- launch
extern "C" void kernel_launch(void* const* d_in, const int* in_sizes, int n_in,
                              void* d_out, int out_size, void* d_ws, size_t ws_size,
                              hipStream_t stream) {
  const float* x     = (const float*)d_in[0];
  const float* te    = (const float*)d_in[1];
  const float* keys  = (const float*)d_in[2];
  const float* vals  = (const float*)d_in[3];
  const void*  mask  = d_in[4];
  const float* w_in  = (const float*)d_in[5];
  const float* b_in  = (const float*)d_in[6];
  const float* w_out = (const float*)d_in[7];
  const float* b_out = (const float*)d_in[8];

  // workspace layout (132.3 MB): buf0 = x16 then ctx16; buf1 = h16 then attn16
  char* ws = (char*)d_ws;
  const size_t MB32 = 33554432;
  _Float16* buf0   = (_Float16*)(ws);
  _Float16* buf1   = (_Float16*)(ws + MB32);
  _Float16* keysT  = (_Float16*)(ws + 2 * MB32);
  _Float16* valsT  = (_Float16*)(ws + 3 * MB32);
  _Float16* win16  = (_Float16*)(ws + 4 * MB32);
  _Float16* wout16 = (_Float16*)(ws + 4 * MB32 + 2097152);
  float*    maskneg= (float*)   (ws + 4 * MB32 + 2 * 2097152);
  float*    sscale = (float*)   (ws + 4 * MB32 + 2 * 2097152 + 65536);

  float* out_main = (float*)d_out;
  float* attn_out = (float*)d_out + (size_t)BB * TT * CC;

  // prepass: casts + transposes + mask
  cvt_f16<<<dim3(16777216 / 2048), 256, 0, stream>>>(x, buf0, 16777216);
  cvt_f16<<<dim3(1048576 / 2048), 256, 0, stream>>>(w_in, win16, 1048576);
  cvt_f16<<<dim3(1048576 / 2048), 256, 0, stream>>>(w_out, wout16, 1048576);
  transpose_cvt<<<dim3(SS / 64, EE / 64, BB), 256, 0, stream>>>(keys, keysT, EE, SS);
  transpose_cvt<<<dim3(EE / 64, SS / 64, BB), 256, 0, stream>>>(vals, valsT, SS, EE);
  mask_prep<<<dim3(BB), 256, 0, stream>>>((const unsigned char*)mask, maskneg, sscale);

  // GEMM1: h16 = (x16 @ w_in^T + b_in + te) * scale   [16384 x 1024, K=1024]
  gemm_nt<1><<<dim3(EE / 128, (BB * TT) / 128, 1), 256, 0, stream>>>(
      buf0, win16, 0, 0, 0, BB * TT, EE, CC, buf1, b_in, te, nullptr);
  // GEMM2: scores = h16 @ keysT^T + maskneg  -> d_out attn region (f32)
  gemm_nt<2><<<dim3(SS / 128, TT / 128, BB), 256, 0, stream>>>(
      buf1, keysT, (long)TT * EE, (long)SS * EE, (long)TT * SS,
      TT, SS, EE, attn_out, nullptr, nullptr, maskneg);
  // softmax rows (in-place f32) + fp16 copy into buf1
  softmax_k<<<dim3(BB * TT), 256, 0, stream>>>(attn_out, buf1);
  // GEMM3: ctx16 = (attn16 @ valsT^T) * sqrt(s_b)
  gemm_nt<3><<<dim3(EE / 128, TT / 128, BB), 256, 0, stream>>>(
      buf1, valsT, (long)TT * SS, (long)EE * SS, (long)TT * EE,
      TT, EE, SS, buf0, nullptr, nullptr, sscale);
  // GEMM4: out = (ctx16 @ w_out^T + b_out + x) * scale  (f32)
  gemm_nt<4><<<dim3(CC / 128, (BB * TT) / 128, 1), 256, 0, stream>>>(
      buf0, wout16, 0, 0, 0, BB * TT, CC, EE, out_main, b_out, x, nullptr);
}

// Round 2
// 388.540 us; speedup vs baseline: 1.0174x; 1.0174x over previous
//
#include <hip/hip_runtime.h>

// AttentionLayer: B=16, T=S=C=E=1024, NORM_C=0.5
// out  = (ctx @ w_out^T + b_out + x) * sqrt(.5)   [f32, first 16M elems of d_out]
// attn = softmax(mask(h @ K))                     [f32, next 16M elems]
// h = (x @ w_in^T + b_in + te) * sqrt(.5); ctx = (attn @ V) * sqrt(S - sum(mask))
// fp16 MFMA (16x16x32) for all 4 GEMMs, f32 accumulate, f32 softmax.
// R2: vectorized LDS-transpose epilogue + XCD-aware block swizzle.

#define SCALE_F 0.70710678118654752440f

constexpr int BB = 16, TT = 1024, SS = 1024, CC = 1024, EE = 1024;

typedef float    f32x4 __attribute__((ext_vector_type(4)));
typedef _Float16 f16x8 __attribute__((ext_vector_type(8)));
typedef _Float16 f16x4 __attribute__((ext_vector_type(4)));

__device__ __forceinline__ void gload_lds16(const _Float16* g, _Float16* l) {
  __builtin_amdgcn_global_load_lds((const __attribute__((address_space(1))) void*)g,
                                   (__attribute__((address_space(3))) void*)l,
                                   16, 0, 0);
}

// ---------------------------------------------------------------- conversions
__global__ __launch_bounds__(256) void cvt_f16(const float* __restrict__ s,
                                               _Float16* __restrict__ d, long n) {
  long i = ((long)blockIdx.x * 256 + threadIdx.x) * 8;
  if (i >= n) return;
  f32x4 a = *(const f32x4*)(s + i);
  f32x4 b = *(const f32x4*)(s + i + 4);
  f16x8 h;
  h[0]=(_Float16)a[0]; h[1]=(_Float16)a[1]; h[2]=(_Float16)a[2]; h[3]=(_Float16)a[3];
  h[4]=(_Float16)b[0]; h[5]=(_Float16)b[1]; h[6]=(_Float16)b[2]; h[7]=(_Float16)b[3];
  *(f16x8*)(d + i) = h;
}

// src: [B][R][Cc] f32  ->  dst: [B][Cc][R] f16   (64x64 LDS tile transpose)
__global__ __launch_bounds__(256) void transpose_cvt(const float* __restrict__ src,
                                                     _Float16* __restrict__ dst,
                                                     int R, int Cc) {
  __shared__ float tile[64][65];
  const int b = blockIdx.z;
  const int r0 = blockIdx.y * 64, c0 = blockIdx.x * 64;
  const int t = threadIdx.x;
  const int tr = t >> 4, tc4 = (t & 15) * 4;
  const float* s = src + (size_t)b * R * Cc;
#pragma unroll
  for (int i = 0; i < 4; ++i) {
    f32x4 v = *(const f32x4*)(s + (size_t)(r0 + i * 16 + tr) * Cc + c0 + tc4);
    tile[i * 16 + tr][tc4 + 0] = v[0]; tile[i * 16 + tr][tc4 + 1] = v[1];
    tile[i * 16 + tr][tc4 + 2] = v[2]; tile[i * 16 + tr][tc4 + 3] = v[3];
  }
  __syncthreads();
  _Float16* d = dst + (size_t)b * Cc * R;
#pragma unroll
  for (int j = 0; j < 4; ++j) {
    const int cl = j * 16 + tr;  // dst row (source column)
    f16x4 h;
    h[0] = (_Float16)tile[tc4 + 0][cl]; h[1] = (_Float16)tile[tc4 + 1][cl];
    h[2] = (_Float16)tile[tc4 + 2][cl]; h[3] = (_Float16)tile[tc4 + 3][cl];
    *(f16x4*)(d + (size_t)(c0 + cl) * R + r0 + tc4) = h;
  }
}

// ------------------------------------------------------------------- mask prep
__global__ __launch_bounds__(256) void mask_prep(const unsigned char* __restrict__ mraw,
                                                 float* __restrict__ maskneg,
                                                 float* __restrict__ sscale) {
  const int b = blockIdx.x, t = threadIdx.x;
  __shared__ int bytemode_sh, cnt_sh;
  if (t == 0) { bytemode_sh = 0; cnt_sh = 0; }
  __syncthreads();
  const unsigned int* mu = (const unsigned int*)mraw;
  int local = 0;
  for (int i = t; i < (BB * SS) / 4; i += 256) {
    unsigned int v = mu[i];
    if (v != 0u && v != 1u && v != 0x3f800000u) local = 1;
  }
  if (local) atomicOr(&bytemode_sh, 1);
  __syncthreads();
  const int bytemode = bytemode_sh;
  int cnt = 0;
  for (int s = t; s < SS; s += 256) {
    int m = bytemode ? (mraw[b * SS + s] != 0) : (mu[b * SS + s] != 0u);
    maskneg[b * SS + s] = m ? -__builtin_inff() : 0.0f;
    cnt += m;
  }
#pragma unroll
  for (int o = 32; o; o >>= 1) cnt += __shfl_down(cnt, o);
  if ((t & 63) == 0) atomicAdd(&cnt_sh, cnt);
  __syncthreads();
  if (t == 0) {
    float sv = (float)SS - (float)cnt_sh;
    sscale[b] = sv * rsqrtf(sv);
  }
}

// ---------------------------------------------------------------------- GEMM
// C[M,N] = A[M,K] @ Bmat[N,K]^T ; fp16 operands K-major, f32 accum.
// 128x128 tile, BK=64, 256 thr (4 waves, 2x2), global_load_lds width 16.
template <int EPI>
__global__ __launch_bounds__(256)
void gemm_nt(const _Float16* __restrict__ A, const _Float16* __restrict__ Bmat,
             long aStride, long bStride, long oStride,
             int M, int N, int K,
             void* __restrict__ outp,
             const float* __restrict__ bias,
             const float* __restrict__ addmat,
             const float* __restrict__ extra) {
  constexpr int BM = 128, BN = 128, BK = 64;
  constexpr int EPS = 68;  // epilogue LDS row stride (floats): 2-way banks, 16B aligned
  __shared__ __attribute__((aligned(16))) char smem[(BM + BN) * BK * 2];  // 32 KB
  _Float16* As = (_Float16*)smem;
  _Float16* Bs = (_Float16*)(smem + BM * BK * 2);

  const int t = threadIdx.x;
  const int lane = t & 63;
  const int wid = t >> 6;
  const int wr = wid >> 1, wc = wid & 1;
  const int z = blockIdx.z;

  // XCD-aware bijective swizzle; gridDim.x == 8 in every launch here.
  const int gy = gridDim.y;
  const int fblk = blockIdx.x + (blockIdx.y << 3);
  const int wg = (fblk & 7) * gy + (fblk >> 3);
  const long rowBase = (long)(wg >> 3) * BM;
  const long colBase = (long)(wg & 7) * BN;

  const _Float16* Ag = A + (size_t)z * aStride + rowBase * K;
  const _Float16* Bg = Bmat + (size_t)z * bStride + colBase * K;

  const int srow = t >> 3;          // 0..31
  const int scol = (t & 7) * 8;     // 0..56

  f32x4 acc[4][4] = {};

  for (int k0 = 0; k0 < K; k0 += BK) {
#pragma unroll
    for (int q = 0; q < 4; ++q)
      gload_lds16(Ag + (size_t)(q * 32 + srow) * K + k0 + scol, &As[(q * 256 + t) * 8]);
#pragma unroll
    for (int q = 0; q < 4; ++q)
      gload_lds16(Bg + (size_t)(q * 32 + srow) * K + k0 + scol, &Bs[(q * 256 + t) * 8]);
    asm volatile("s_waitcnt vmcnt(0)" ::: "memory");
    __syncthreads();
#pragma unroll
    for (int ks = 0; ks < 2; ++ks) {
      f16x8 a[4], b[4];
#pragma unroll
      for (int m = 0; m < 4; ++m)
        a[m] = *(const f16x8*)&As[(wr * 64 + m * 16 + (lane & 15)) * BK + ks * 32 + (lane >> 4) * 8];
#pragma unroll
      for (int n = 0; n < 4; ++n)
        b[n] = *(const f16x8*)&Bs[(wc * 64 + n * 16 + (lane & 15)) * BK + ks * 32 + (lane >> 4) * 8];
#pragma unroll
      for (int m = 0; m < 4; ++m)
#pragma unroll
        for (int n = 0; n < 4; ++n)
          acc[m][n] = __builtin_amdgcn_mfma_f32_16x16x32_f16(a[m], b[n], acc[m][n], 0, 0, 0);
    }
    __syncthreads();
  }

  // ---- vectorized epilogue: wave-private LDS transpose to row-major chunks.
  // acc[m][n][j] = C[row = wr*64+m*16+fq+j][col = wc*64+n*16+fr]  (m89 layout)
  const int fr = lane & 15;
  const int fq = (lane >> 4) * 4;
  const int er = lane >> 2;         // row 0..15 within the 16-row slab
  const int ec = (lane & 3) * 16;   // 16-col chunk start within the 64-col span
  const long gc0 = colBase + wc * 64 + ec;
  float* ep = (float*)smem + wid * (16 * EPS);

  f32x4 biasv[4], maskv[4], av[4];
  float sc = 0.f;
  if constexpr (EPI == 1 || EPI == 4) {
#pragma unroll
    for (int i = 0; i < 4; ++i) biasv[i] = *(const f32x4*)&bias[gc0 + i * 4];
    const long gr0 = rowBase + wr * 64 + er;
#pragma unroll
    for (int i = 0; i < 4; ++i) av[i] = *(const f32x4*)&addmat[gr0 * N + gc0 + i * 4];
  }
  if constexpr (EPI == 2) {
#pragma unroll
    for (int i = 0; i < 4; ++i) maskv[i] = *(const f32x4*)&extra[(size_t)z * N + gc0 + i * 4];
  }
  if constexpr (EPI == 3) sc = extra[z];

#pragma unroll
  for (int m = 0; m < 4; ++m) {
#pragma unroll
    for (int n = 0; n < 4; ++n)
#pragma unroll
      for (int j = 0; j < 4; ++j)
        ep[(fq + j) * EPS + n * 16 + fr] = acc[m][n][j];
    __syncthreads();
    const long gr = rowBase + wr * 64 + m * 16 + er;
    f32x4 r[4];
#pragma unroll
    for (int i = 0; i < 4; ++i) r[i] = *(const f32x4*)&ep[er * EPS + ec + i * 4];
    f32x4 a_cur[4];
    if constexpr (EPI == 1 || EPI == 4) {
#pragma unroll
      for (int i = 0; i < 4; ++i) a_cur[i] = av[i];
      if (m < 3) {                       // prefetch next row's addmat
        const long grn = gr + 16;
#pragma unroll
        for (int i = 0; i < 4; ++i) av[i] = *(const f32x4*)&addmat[grn * N + gc0 + i * 4];
      }
    }
    if constexpr (EPI == 1) {
      _Float16* o = (_Float16*)outp + gr * N + gc0;
#pragma unroll
      for (int g = 0; g < 2; ++g) {
        f32x4 v0 = (r[2 * g] + biasv[2 * g] + a_cur[2 * g]) * SCALE_F;
        f32x4 v1 = (r[2 * g + 1] + biasv[2 * g + 1] + a_cur[2 * g + 1]) * SCALE_F;
        f16x8 h;
        h[0]=(_Float16)v0[0]; h[1]=(_Float16)v0[1]; h[2]=(_Float16)v0[2]; h[3]=(_Float16)v0[3];
        h[4]=(_Float16)v1[0]; h[5]=(_Float16)v1[1]; h[6]=(_Float16)v1[2]; h[7]=(_Float16)v1[3];
        *(f16x8*)(o + g * 8) = h;
      }
    } else if constexpr (EPI == 2) {
      float* o = (float*)outp + (size_t)z * oStride + gr * N + gc0;
#pragma unroll
      for (int i = 0; i < 4; ++i) *(f32x4*)(o + i * 4) = r[i] + maskv[i];
    } else if constexpr (EPI == 3) {
      _Float16* o = (_Float16*)outp + (size_t)z * oStride + gr * N + gc0;
#pragma unroll
      for (int g = 0; g < 2; ++g) {
        f32x4 v0 = r[2 * g] * sc;
        f32x4 v1 = r[2 * g + 1] * sc;
        f16x8 h;
        h[0]=(_Float16)v0[0]; h[1]=(_Float16)v0[1]; h[2]=(_Float16)v0[2]; h[3]=(_Float16)v0[3];
        h[4]=(_Float16)v1[0]; h[5]=(_Float16)v1[1]; h[6]=(_Float16)v1[2]; h[7]=(_Float16)v1[3];
        *(f16x8*)(o + g * 8) = h;
      }
    } else {
      float* o = (float*)outp + gr * N + gc0;
#pragma unroll
      for (int i = 0; i < 4; ++i)
        *(f32x4*)(o + i * 4) = (r[i] + biasv[i] + a_cur[i]) * SCALE_F;
    }
    __syncthreads();  // wave-private region, but keep write(m+1) after read(m) robustly
  }
}

// -------------------------------------------------------------------- softmax
__global__ __launch_bounds__(256) void softmax_k(float* __restrict__ attn,
                                                 _Float16* __restrict__ attn16) {
  const size_t row = blockIdx.x;
  float* p = attn + row * SS;
  const int t = threadIdx.x;
  f32x4 v = *(const f32x4*)(p + t * 4);
  __shared__ float red[8];
  float m = fmaxf(fmaxf(v[0], v[1]), fmaxf(v[2], v[3]));
#pragma unroll
  for (int o = 32; o; o >>= 1) m = fmaxf(m, __shfl_xor(m, o));
  if (!(t & 63)) red[t >> 6] = m;
  __syncthreads();
  m = fmaxf(fmaxf(red[0], red[1]), fmaxf(red[2], red[3]));
  f32x4 e;
  e[0] = __expf(v[0] - m); e[1] = __expf(v[1] - m);
  e[2] = __expf(v[2] - m); e[3] = __expf(v[3] - m);
  float s = e[0] + e[1] + e[2] + e[3];
#pragma unroll
  for (int o = 32; o; o >>= 1) s += __shfl_xor(s, o);
  if (!(t & 63)) red[4 + (t >> 6)] = s;
  __syncthreads();
  s = red[4] + red[5] + red[6] + red[7];
  const float inv = 1.0f / s;
  f32x4 o4; o4[0]=e[0]*inv; o4[1]=e[1]*inv; o4[2]=e[2]*inv; o4[3]=e[3]*inv;
  *(f32x4*)(p + t * 4) = o4;
  f16x4 h; h[0]=(_Float16)o4[0]; h[1]=(_Float16)o4[1];
  h[2]=(_Float16)o4[2]; h[3]=(_Float16)o4[3];
  *(f16x4*)(attn16 + row * SS + t * 4) = h;
}

// -------------------------------------------------------------------- launch
extern "C" void kernel_launch(void* const* d_in, const int* in_sizes, int n_in,
                              void* d_out, int out_size, void* d_ws, size_t ws_size,
                              hipStream_t stream) {
  const float* x     = (const float*)d_in[0];
  const float* te    = (const float*)d_in[1];
  const float* keys  = (const float*)d_in[2];
  const float* vals  = (const float*)d_in[3];
  const void*  mask  = d_in[4];
  const float* w_in  = (const float*)d_in[5];
  const float* b_in  = (const float*)d_in[6];
  const float* w_out = (const float*)d_in[7];
  const float* b_out = (const float*)d_in[8];

  char* ws = (char*)d_ws;
  const size_t MB32 = 33554432;
  _Float16* buf0   = (_Float16*)(ws);
  _Float16* buf1   = (_Float16*)(ws + MB32);
  _Float16* keysT  = (_Float16*)(ws + 2 * MB32);
  _Float16* valsT  = (_Float16*)(ws + 3 * MB32);
  _Float16* win16  = (_Float16*)(ws + 4 * MB32);
  _Float16* wout16 = (_Float16*)(ws + 4 * MB32 + 2097152);
  float*    maskneg= (float*)   (ws + 4 * MB32 + 2 * 2097152);
  float*    sscale = (float*)   (ws + 4 * MB32 + 2 * 2097152 + 65536);

  float* out_main = (float*)d_out;
  float* attn_out = (float*)d_out + (size_t)BB * TT * CC;

  cvt_f16<<<dim3(16777216 / 2048), 256, 0, stream>>>(x, buf0, 16777216);
  cvt_f16<<<dim3(1048576 / 2048), 256, 0, stream>>>(w_in, win16, 1048576);
  cvt_f16<<<dim3(1048576 / 2048), 256, 0, stream>>>(w_out, wout16, 1048576);
  transpose_cvt<<<dim3(SS / 64, EE / 64, BB), 256, 0, stream>>>(keys, keysT, EE, SS);
  transpose_cvt<<<dim3(EE / 64, SS / 64, BB), 256, 0, stream>>>(vals, valsT, SS, EE);
  mask_prep<<<dim3(BB), 256, 0, stream>>>((const unsigned char*)mask, maskneg, sscale);

  gemm_nt<1><<<dim3(EE / 128, (BB * TT) / 128, 1), 256, 0, stream>>>(
      buf0, win16, 0, 0, 0, BB * TT, EE, CC, buf1, b_in, te, nullptr);
  gemm_nt<2><<<dim3(SS / 128, TT / 128, BB), 256, 0, stream>>>(
      buf1, keysT, (long)TT * EE, (long)SS * EE, (long)TT * SS,
      TT, SS, EE, attn_out, nullptr, nullptr, maskneg);
  softmax_k<<<dim3(BB * TT), 256, 0, stream>>>(attn_out, buf1);
  gemm_nt<3><<<dim3(EE / 128, TT / 128, BB), 256, 0, stream>>>(
      buf1, valsT, (long)TT * SS, (long)EE * SS, (long)TT * EE,
      TT, EE, SS, buf0, nullptr, nullptr, sscale);
  gemm_nt<4><<<dim3(CC / 128, (BB * TT) / 128, 1), 256, 0, stream>>>(
      buf0, wout16, 0, 0, 0, BB * TT, CC, EE, out_main, b_out, x, nullptr);
}

// Round 3
// 337.134 us; speedup vs baseline: 1.1726x; 1.1525x over previous
//
#include <hip/hip_runtime.h>

// AttentionLayer: B=16, T=S=C=E=1024, NORM_C=0.5
// out  = (ctx @ w_out^T + b_out + x) * sqrt(.5)   [f32, first 16M elems of d_out]
// attn = softmax(mask(h @ K))                     [f32, next 16M elems]
// fp16 MFMA (16x16x32), f32 accumulate, f32 softmax.
// R3: double-buffered K-loop (stage-before-compute) + T2 both-sides LDS swizzle.

#define SCALE_F 0.70710678118654752440f

constexpr int BB = 16, TT = 1024, SS = 1024, CC = 1024, EE = 1024;

typedef float    f32x4 __attribute__((ext_vector_type(4)));
typedef _Float16 f16x8 __attribute__((ext_vector_type(8)));
typedef _Float16 f16x4 __attribute__((ext_vector_type(4)));

__device__ __forceinline__ void gload_lds16(const _Float16* g, _Float16* l) {
  __builtin_amdgcn_global_load_lds((const __attribute__((address_space(1))) void*)g,
                                   (__attribute__((address_space(3))) void*)l,
                                   16, 0, 0);
}

// ---------------------------------------------------------------- conversions
__global__ __launch_bounds__(256) void cvt_f16(const float* __restrict__ s,
                                               _Float16* __restrict__ d, long n) {
  long i = ((long)blockIdx.x * 256 + threadIdx.x) * 8;
  if (i >= n) return;
  f32x4 a = *(const f32x4*)(s + i);
  f32x4 b = *(const f32x4*)(s + i + 4);
  f16x8 h;
  h[0]=(_Float16)a[0]; h[1]=(_Float16)a[1]; h[2]=(_Float16)a[2]; h[3]=(_Float16)a[3];
  h[4]=(_Float16)b[0]; h[5]=(_Float16)b[1]; h[6]=(_Float16)b[2]; h[7]=(_Float16)b[3];
  *(f16x8*)(d + i) = h;
}

// src: [B][R][Cc] f32  ->  dst: [B][Cc][R] f16   (64x64 LDS tile transpose)
__global__ __launch_bounds__(256) void transpose_cvt(const float* __restrict__ src,
                                                     _Float16* __restrict__ dst,
                                                     int R, int Cc) {
  __shared__ float tile[64][65];
  const int b = blockIdx.z;
  const int r0 = blockIdx.y * 64, c0 = blockIdx.x * 64;
  const int t = threadIdx.x;
  const int tr = t >> 4, tc4 = (t & 15) * 4;
  const float* s = src + (size_t)b * R * Cc;
#pragma unroll
  for (int i = 0; i < 4; ++i) {
    f32x4 v = *(const f32x4*)(s + (size_t)(r0 + i * 16 + tr) * Cc + c0 + tc4);
    tile[i * 16 + tr][tc4 + 0] = v[0]; tile[i * 16 + tr][tc4 + 1] = v[1];
    tile[i * 16 + tr][tc4 + 2] = v[2]; tile[i * 16 + tr][tc4 + 3] = v[3];
  }
  __syncthreads();
  _Float16* d = dst + (size_t)b * Cc * R;
#pragma unroll
  for (int j = 0; j < 4; ++j) {
    const int cl = j * 16 + tr;
    f16x4 h;
    h[0] = (_Float16)tile[tc4 + 0][cl]; h[1] = (_Float16)tile[tc4 + 1][cl];
    h[2] = (_Float16)tile[tc4 + 2][cl]; h[3] = (_Float16)tile[tc4 + 3][cl];
    *(f16x4*)(d + (size_t)(c0 + cl) * R + r0 + tc4) = h;
  }
}

// ------------------------------------------------------------------- mask prep
__global__ __launch_bounds__(256) void mask_prep(const unsigned char* __restrict__ mraw,
                                                 float* __restrict__ maskneg,
                                                 float* __restrict__ sscale) {
  const int b = blockIdx.x, t = threadIdx.x;
  __shared__ int bytemode_sh, cnt_sh;
  if (t == 0) { bytemode_sh = 0; cnt_sh = 0; }
  __syncthreads();
  const unsigned int* mu = (const unsigned int*)mraw;
  int local = 0;
  for (int i = t; i < (BB * SS) / 4; i += 256) {
    unsigned int v = mu[i];
    if (v != 0u && v != 1u && v != 0x3f800000u) local = 1;
  }
  if (local) atomicOr(&bytemode_sh, 1);
  __syncthreads();
  const int bytemode = bytemode_sh;
  int cnt = 0;
  for (int s = t; s < SS; s += 256) {
    int m = bytemode ? (mraw[b * SS + s] != 0) : (mu[b * SS + s] != 0u);
    maskneg[b * SS + s] = m ? -__builtin_inff() : 0.0f;
    cnt += m;
  }
#pragma unroll
  for (int o = 32; o; o >>= 1) cnt += __shfl_down(cnt, o);
  if ((t & 63) == 0) atomicAdd(&cnt_sh, cnt);
  __syncthreads();
  if (t == 0) {
    float sv = (float)SS - (float)cnt_sh;
    sscale[b] = sv * rsqrtf(sv);
  }
}

// ---------------------------------------------------------------------- GEMM
// C[M,N] = A[M,K] @ Bmat[N,K]^T ; fp16 K-major, f32 accum.
// 128x128 tile, BK=64, 256 thr (4 waves, 2x2).
// Double-buffered: STAGE(next) -> compute(cur) -> barrier (drains vmcnt).
// T2 swizzle: linear LDS dest; global src col = 8*((t&7)^(row&7));
//             ds_read slot = (ks*4+hi) ^ (row&7).  (involution both sides)
template <int EPI>
__global__ __launch_bounds__(256)
void gemm_nt(const _Float16* __restrict__ A, const _Float16* __restrict__ Bmat,
             long aStride, long bStride, long oStride,
             int M, int N, int K,
             void* __restrict__ outp,
             const float* __restrict__ bias,
             const float* __restrict__ addmat,
             const float* __restrict__ extra) {
  constexpr int BM = 128, BN = 128, BK = 64;
  constexpr int EPS = 68;
  __shared__ __attribute__((aligned(16))) _Float16 smem[2][(BM + BN) * BK];  // 64 KB

  const int t = threadIdx.x;
  const int lane = t & 63;
  const int wid = t >> 6;
  const int wr = wid >> 1, wc = wid & 1;
  const int z = blockIdx.z;

  // XCD-aware bijective swizzle; gridDim.x == 8 in every launch here.
  const int gy = gridDim.y;
  const int fblk = blockIdx.x + (blockIdx.y << 3);
  const int wg = (fblk & 7) * gy + (fblk >> 3);
  const long rowBase = (long)(wg >> 3) * BM;
  const long colBase = (long)(wg & 7) * BN;

  const _Float16* Ag = A + (size_t)z * aStride + rowBase * K;
  const _Float16* Bg = Bmat + (size_t)z * bStride + colBase * K;

  const int srow = t >> 3;                         // 0..31 (row % 32 within q-slab)
  const int scol = 8 * ((t & 7) ^ (srow & 7));     // inverse-swizzled source col

  f32x4 acc[4][4] = {};

  const int lo = lane & 15, hi = lane >> 4;
  const int sx = lo & 7;                           // row&7 for fragment rows

  auto stage = [&](int buf, int k0) {
    _Float16* As = &smem[buf][0];
    _Float16* Bs = &smem[buf][BM * BK];
#pragma unroll
    for (int q = 0; q < 4; ++q)
      gload_lds16(Ag + (size_t)(q * 32 + srow) * K + k0 + scol, &As[(q * 256 + t) * 8]);
#pragma unroll
    for (int q = 0; q < 4; ++q)
      gload_lds16(Bg + (size_t)(q * 32 + srow) * K + k0 + scol, &Bs[(q * 256 + t) * 8]);
  };

  stage(0, 0);
  asm volatile("s_waitcnt vmcnt(0)" ::: "memory");
  __syncthreads();

  int cur = 0;
  for (int k0 = 0; k0 < K; k0 += BK) {
    if (k0 + BK < K) stage(cur ^ 1, k0 + BK);      // prefetch next tile
    const _Float16* As = &smem[cur][0];
    const _Float16* Bs = &smem[cur][BM * BK];
#pragma unroll
    for (int ks = 0; ks < 2; ++ks) {
      f16x8 a[4], b[4];
#pragma unroll
      for (int m = 0; m < 4; ++m) {
        const int slotA = (ks * 4 + hi) ^ sx;
        a[m] = *(const f16x8*)&As[(wr * 64 + m * 16 + lo) * BK + slotA * 8];
      }
#pragma unroll
      for (int n = 0; n < 4; ++n) {
        const int slotB = (ks * 4 + hi) ^ sx;
        b[n] = *(const f16x8*)&Bs[(wc * 64 + n * 16 + lo) * BK + slotB * 8];
      }
#pragma unroll
      for (int m = 0; m < 4; ++m)
#pragma unroll
        for (int n = 0; n < 4; ++n)
          acc[m][n] = __builtin_amdgcn_mfma_f32_16x16x32_f16(a[m], b[n], acc[m][n], 0, 0, 0);
    }
    __syncthreads();   // drains vmcnt (next-tile loads) + lgkm; flips buffer safely
    cur ^= 1;
  }

  // ---- vectorized epilogue: wave-private LDS transpose to row-major chunks.
  const int fr = lane & 15;
  const int fq = (lane >> 4) * 4;
  const int er = lane >> 2;
  const int ec = (lane & 3) * 16;
  const long gc0 = colBase + wc * 64 + ec;
  float* ep = (float*)&smem[0][0] + wid * (16 * EPS);

  f32x4 biasv[4], maskv[4], av[4];
  float sc = 0.f;
  if constexpr (EPI == 1 || EPI == 4) {
#pragma unroll
    for (int i = 0; i < 4; ++i) biasv[i] = *(const f32x4*)&bias[gc0 + i * 4];
    const long gr0 = rowBase + wr * 64 + er;
#pragma unroll
    for (int i = 0; i < 4; ++i) av[i] = *(const f32x4*)&addmat[gr0 * N + gc0 + i * 4];
  }
  if constexpr (EPI == 2) {
#pragma unroll
    for (int i = 0; i < 4; ++i) maskv[i] = *(const f32x4*)&extra[(size_t)z * N + gc0 + i * 4];
  }
  if constexpr (EPI == 3) sc = extra[z];

#pragma unroll
  for (int m = 0; m < 4; ++m) {
#pragma unroll
    for (int n = 0; n < 4; ++n)
#pragma unroll
      for (int j = 0; j < 4; ++j)
        ep[(fq + j) * EPS + n * 16 + fr] = acc[m][n][j];
    __syncthreads();
    const long gr = rowBase + wr * 64 + m * 16 + er;
    f32x4 r[4];
#pragma unroll
    for (int i = 0; i < 4; ++i) r[i] = *(const f32x4*)&ep[er * EPS + ec + i * 4];
    f32x4 a_cur[4];
    if constexpr (EPI == 1 || EPI == 4) {
#pragma unroll
      for (int i = 0; i < 4; ++i) a_cur[i] = av[i];
      if (m < 3) {
        const long grn = gr + 16;
#pragma unroll
        for (int i = 0; i < 4; ++i) av[i] = *(const f32x4*)&addmat[grn * N + gc0 + i * 4];
      }
    }
    if constexpr (EPI == 1) {
      _Float16* o = (_Float16*)outp + gr * N + gc0;
#pragma unroll
      for (int g = 0; g < 2; ++g) {
        f32x4 v0 = (r[2 * g] + biasv[2 * g] + a_cur[2 * g]) * SCALE_F;
        f32x4 v1 = (r[2 * g + 1] + biasv[2 * g + 1] + a_cur[2 * g + 1]) * SCALE_F;
        f16x8 h;
        h[0]=(_Float16)v0[0]; h[1]=(_Float16)v0[1]; h[2]=(_Float16)v0[2]; h[3]=(_Float16)v0[3];
        h[4]=(_Float16)v1[0]; h[5]=(_Float16)v1[1]; h[6]=(_Float16)v1[2]; h[7]=(_Float16)v1[3];
        *(f16x8*)(o + g * 8) = h;
      }
    } else if constexpr (EPI == 2) {
      float* o = (float*)outp + (size_t)z * oStride + gr * N + gc0;
#pragma unroll
      for (int i = 0; i < 4; ++i) *(f32x4*)(o + i * 4) = r[i] + maskv[i];
    } else if constexpr (EPI == 3) {
      _Float16* o = (_Float16*)outp + (size_t)z * oStride + gr * N + gc0;
#pragma unroll
      for (int g = 0; g < 2; ++g) {
        f32x4 v0 = r[2 * g] * sc;
        f32x4 v1 = r[2 * g + 1] * sc;
        f16x8 h;
        h[0]=(_Float16)v0[0]; h[1]=(_Float16)v0[1]; h[2]=(_Float16)v0[2]; h[3]=(_Float16)v0[3];
        h[4]=(_Float16)v1[0]; h[5]=(_Float16)v1[1]; h[6]=(_Float16)v1[2]; h[7]=(_Float16)v1[3];
        *(f16x8*)(o + g * 8) = h;
      }
    } else {
      float* o = (float*)outp + gr * N + gc0;
#pragma unroll
      for (int i = 0; i < 4; ++i)
        *(f32x4*)(o + i * 4) = (r[i] + biasv[i] + a_cur[i]) * SCALE_F;
    }
    __syncthreads();
  }
}

// -------------------------------------------------------------------- softmax
__global__ __launch_bounds__(256) void softmax_k(float* __restrict__ attn,
                                                 _Float16* __restrict__ attn16) {
  const size_t row = blockIdx.x;
  float* p = attn + row * SS;
  const int t = threadIdx.x;
  f32x4 v = *(const f32x4*)(p + t * 4);
  __shared__ float red[8];
  float m = fmaxf(fmaxf(v[0], v[1]), fmaxf(v[2], v[3]));
#pragma unroll
  for (int o = 32; o; o >>= 1) m = fmaxf(m, __shfl_xor(m, o));
  if (!(t & 63)) red[t >> 6] = m;
  __syncthreads();
  m = fmaxf(fmaxf(red[0], red[1]), fmaxf(red[2], red[3]));
  f32x4 e;
  e[0] = __expf(v[0] - m); e[1] = __expf(v[1] - m);
  e[2] = __expf(v[2] - m); e[3] = __expf(v[3] - m);
  float s = e[0] + e[1] + e[2] + e[3];
#pragma unroll
  for (int o = 32; o; o >>= 1) s += __shfl_xor(s, o);
  if (!(t & 63)) red[4 + (t >> 6)] = s;
  __syncthreads();
  s = red[4] + red[5] + red[6] + red[7];
  const float inv = 1.0f / s;
  f32x4 o4; o4[0]=e[0]*inv; o4[1]=e[1]*inv; o4[2]=e[2]*inv; o4[3]=e[3]*inv;
  *(f32x4*)(p + t * 4) = o4;
  f16x4 h; h[0]=(_Float16)o4[0]; h[1]=(_Float16)o4[1];
  h[2]=(_Float16)o4[2]; h[3]=(_Float16)o4[3];
  *(f16x4*)(attn16 + row * SS + t * 4) = h;
}

// -------------------------------------------------------------------- launch
extern "C" void kernel_launch(void* const* d_in, const int* in_sizes, int n_in,
                              void* d_out, int out_size, void* d_ws, size_t ws_size,
                              hipStream_t stream) {
  const float* x     = (const float*)d_in[0];
  const float* te    = (const float*)d_in[1];
  const float* keys  = (const float*)d_in[2];
  const float* vals  = (const float*)d_in[3];
  const void*  mask  = d_in[4];
  const float* w_in  = (const float*)d_in[5];
  const float* b_in  = (const float*)d_in[6];
  const float* w_out = (const float*)d_in[7];
  const float* b_out = (const float*)d_in[8];

  char* ws = (char*)d_ws;
  const size_t MB32 = 33554432;
  _Float16* buf0   = (_Float16*)(ws);
  _Float16* buf1   = (_Float16*)(ws + MB32);
  _Float16* keysT  = (_Float16*)(ws + 2 * MB32);
  _Float16* valsT  = (_Float16*)(ws + 3 * MB32);
  _Float16* win16  = (_Float16*)(ws + 4 * MB32);
  _Float16* wout16 = (_Float16*)(ws + 4 * MB32 + 2097152);
  float*    maskneg= (float*)   (ws + 4 * MB32 + 2 * 2097152);
  float*    sscale = (float*)   (ws + 4 * MB32 + 2 * 2097152 + 65536);

  float* out_main = (float*)d_out;
  float* attn_out = (float*)d_out + (size_t)BB * TT * CC;

  cvt_f16<<<dim3(16777216 / 2048), 256, 0, stream>>>(x, buf0, 16777216);
  cvt_f16<<<dim3(1048576 / 2048), 256, 0, stream>>>(w_in, win16, 1048576);
  cvt_f16<<<dim3(1048576 / 2048), 256, 0, stream>>>(w_out, wout16, 1048576);
  transpose_cvt<<<dim3(SS / 64, EE / 64, BB), 256, 0, stream>>>(keys, keysT, EE, SS);
  transpose_cvt<<<dim3(EE / 64, SS / 64, BB), 256, 0, stream>>>(vals, valsT, SS, EE);
  mask_prep<<<dim3(BB), 256, 0, stream>>>((const unsigned char*)mask, maskneg, sscale);

  gemm_nt<1><<<dim3(EE / 128, (BB * TT) / 128, 1), 256, 0, stream>>>(
      buf0, win16, 0, 0, 0, BB * TT, EE, CC, buf1, b_in, te, nullptr);
  gemm_nt<2><<<dim3(SS / 128, TT / 128, BB), 256, 0, stream>>>(
      buf1, keysT, (long)TT * EE, (long)SS * EE, (long)TT * SS,
      TT, SS, EE, attn_out, nullptr, nullptr, maskneg);
  softmax_k<<<dim3(BB * TT), 256, 0, stream>>>(attn_out, buf1);
  gemm_nt<3><<<dim3(EE / 128, TT / 128, BB), 256, 0, stream>>>(
      buf1, valsT, (long)TT * SS, (long)EE * SS, (long)TT * EE,
      TT, EE, SS, buf0, nullptr, nullptr, sscale);
  gemm_nt<4><<<dim3(CC / 128, (BB * TT) / 128, 1), 256, 0, stream>>>(
      buf0, wout16, 0, 0, 0, BB * TT, CC, EE, out_main, b_out, x, nullptr);
}

// Round 4
// 318.703 us; speedup vs baseline: 1.2404x; 1.0578x over previous
//
#include <hip/hip_runtime.h>

// AttentionLayer: B=16, T=S=C=E=1024, NORM_C=0.5
// out  = (ctx @ w_out^T + b_out + x) * sqrt(.5)   [f32]
// attn = softmax(mask(h @ K))                     [f32]
// R4: 256x256 8-wave 8-phase GEMM (T2+T3+T4+T5), counted vmcnt, K-sliced LDS.

#define SCALE_F 0.70710678118654752440f

constexpr int BB = 16, TT = 1024, SS = 1024, CC = 1024, EE = 1024;

typedef float    f32x4 __attribute__((ext_vector_type(4)));
typedef _Float16 f16x8 __attribute__((ext_vector_type(8)));
typedef _Float16 f16x4 __attribute__((ext_vector_type(4)));

__device__ __forceinline__ void gload_lds16(const _Float16* g, _Float16* l) {
  __builtin_amdgcn_global_load_lds((const __attribute__((address_space(1))) void*)g,
                                   (__attribute__((address_space(3))) void*)l,
                                   16, 0, 0);
}

#define VMCNT(N) asm volatile("s_waitcnt vmcnt(" #N ")" ::: "memory")
#define SBAR()   asm volatile("s_barrier" ::: "memory")

// ---------------------------------------------------------------- conversions
__global__ __launch_bounds__(256) void cvt_f16(const float* __restrict__ s,
                                               _Float16* __restrict__ d, long n) {
  long i = ((long)blockIdx.x * 256 + threadIdx.x) * 8;
  if (i >= n) return;
  f32x4 a = *(const f32x4*)(s + i);
  f32x4 b = *(const f32x4*)(s + i + 4);
  f16x8 h;
  h[0]=(_Float16)a[0]; h[1]=(_Float16)a[1]; h[2]=(_Float16)a[2]; h[3]=(_Float16)a[3];
  h[4]=(_Float16)b[0]; h[5]=(_Float16)b[1]; h[6]=(_Float16)b[2]; h[7]=(_Float16)b[3];
  *(f16x8*)(d + i) = h;
}

// src: [B][R][Cc] f32  ->  dst: [B][Cc][R] f16
__global__ __launch_bounds__(256) void transpose_cvt(const float* __restrict__ src,
                                                     _Float16* __restrict__ dst,
                                                     int R, int Cc) {
  __shared__ float tile[64][65];
  const int b = blockIdx.z;
  const int r0 = blockIdx.y * 64, c0 = blockIdx.x * 64;
  const int t = threadIdx.x;
  const int tr = t >> 4, tc4 = (t & 15) * 4;
  const float* s = src + (size_t)b * R * Cc;
#pragma unroll
  for (int i = 0; i < 4; ++i) {
    f32x4 v = *(const f32x4*)(s + (size_t)(r0 + i * 16 + tr) * Cc + c0 + tc4);
    tile[i * 16 + tr][tc4 + 0] = v[0]; tile[i * 16 + tr][tc4 + 1] = v[1];
    tile[i * 16 + tr][tc4 + 2] = v[2]; tile[i * 16 + tr][tc4 + 3] = v[3];
  }
  __syncthreads();
  _Float16* d = dst + (size_t)b * Cc * R;
#pragma unroll
  for (int j = 0; j < 4; ++j) {
    const int cl = j * 16 + tr;
    f16x4 h;
    h[0] = (_Float16)tile[tc4 + 0][cl]; h[1] = (_Float16)tile[tc4 + 1][cl];
    h[2] = (_Float16)tile[tc4 + 2][cl]; h[3] = (_Float16)tile[tc4 + 3][cl];
    *(f16x4*)(d + (size_t)(c0 + cl) * R + r0 + tc4) = h;
  }
}

// ------------------------------------------------------------------- mask prep
__global__ __launch_bounds__(256) void mask_prep(const unsigned char* __restrict__ mraw,
                                                 float* __restrict__ maskneg,
                                                 float* __restrict__ sscale) {
  const int b = blockIdx.x, t = threadIdx.x;
  __shared__ int bytemode_sh, cnt_sh;
  if (t == 0) { bytemode_sh = 0; cnt_sh = 0; }
  __syncthreads();
  const unsigned int* mu = (const unsigned int*)mraw;
  int local = 0;
  for (int i = t; i < (BB * SS) / 4; i += 256) {
    unsigned int v = mu[i];
    if (v != 0u && v != 1u && v != 0x3f800000u) local = 1;
  }
  if (local) atomicOr(&bytemode_sh, 1);
  __syncthreads();
  const int bytemode = bytemode_sh;
  int cnt = 0;
  for (int s = t; s < SS; s += 256) {
    int m = bytemode ? (mraw[b * SS + s] != 0) : (mu[b * SS + s] != 0u);
    maskneg[b * SS + s] = m ? -__builtin_inff() : 0.0f;
    cnt += m;
  }
#pragma unroll
  for (int o = 32; o; o >>= 1) cnt += __shfl_down(cnt, o);
  if ((t & 63) == 0) atomicAdd(&cnt_sh, cnt);
  __syncthreads();
  if (t == 0) {
    float sv = (float)SS - (float)cnt_sh;
    sscale[b] = sv * rsqrtf(sv);
  }
}

// ------------------------------------------------------------- 256x256 GEMM
// C[M,N] = A[M,K] @ Bmat[N,K]^T ; fp16 K-major, f32 accum. BM=BN=256, BK=64.
// 512 thr = 8 waves (2 wm x 4 wn); per-wave C = 128x64 (acc[8][4] f32x4).
// LDS (128KB): op(A/B) x buf(2) x khalf(2) regions of [256 rows][32 K] f16.
// Swizzle: row r slot s (4x16B/row) holds global k-chunk s ^ ((r>>1)&3)
//   -> read slot = hi ^ ((lo>>1)&3): 8 distinct 16B windows/16 lanes = 2-way free.
// Schedule per iteration I (tiles u=2I in buf0, u+1 in buf1), phases (mh,ks):
//   p1(0,0,b0)+stage Bk0(u+1), vmcnt(4) | p2(0,1,b0)+Ak1(u+1) | p3(1,0,b0)+Bk1(u+1)
//   p4(1,1,b0)+Ak0(u+2), vmcnt(6) | p5(0,0,b1)+Bk0(u+2), vmcnt(4) | p6(0,1,b1)+Ak1(u+2)
//   p7(1,0,b1)+Bk1(u+2) | p8(1,1,b1)+Ak0(u+3), vmcnt(6)
// Ledger: every stage = 2 loads; waits sit >=3 phases behind their targets.
#define STAGE_(OP, KH, TILE)                                                   \
  {                                                                            \
    int tk_ = (TILE); if (tk_ >= nt) tk_ -= nt;                                \
    _Float16* dst_ = &smem[(OP)*32768 + ((TILE)&1)*16384 + (KH)*8192];         \
    const _Float16* src_ = ((OP) ? Bg : Ag) + (size_t)(t >> 2) * K             \
                           + tk_ * 64 + (KH) * 32 + srck;                      \
    gload_lds16(src_, dst_ + (size_t)t * 8);                                   \
    gload_lds16(src_ + (size_t)128 * K, dst_ + (size_t)(512 + t) * 8);         \
  }

#define PHASE_(MH, KS, BUF, SOP, SKH, STILE, WAITCODE)                         \
  {                                                                            \
    const _Float16* Ar_ = &smem[(BUF)*16384 + (KS)*8192];                      \
    const _Float16* Br_ = &smem[32768 + (BUF)*16384 + (KS)*8192];              \
    f16x8 a_[4], b_[4];                                                        \
    _Pragma("unroll") for (int mi_ = 0; mi_ < 4; ++mi_)                        \
      a_[mi_] = *(const f16x8*)&Ar_[(wm*128 + (MH)*64 + mi_*16 + lo)*32 + slotx*8]; \
    _Pragma("unroll") for (int n_ = 0; n_ < 4; ++n_)                           \
      b_[n_] = *(const f16x8*)&Br_[(wn*64 + n_*16 + lo)*32 + slotx*8];         \
    STAGE_(SOP, SKH, STILE);                                                   \
    SBAR();                                                                    \
    asm volatile("s_waitcnt lgkmcnt(0)" ::: "memory");                         \
    __builtin_amdgcn_sched_barrier(0);                                         \
    __builtin_amdgcn_s_setprio(1);                                             \
    _Pragma("unroll") for (int mi_ = 0; mi_ < 4; ++mi_)                        \
      _Pragma("unroll") for (int n_ = 0; n_ < 4; ++n_)                         \
        acc[(MH)*4+mi_][n_] = __builtin_amdgcn_mfma_f32_16x16x32_f16(          \
            a_[mi_], b_[n_], acc[(MH)*4+mi_][n_], 0, 0, 0);                    \
    __builtin_amdgcn_s_setprio(0);                                             \
    WAITCODE;                                                                  \
  }                                                                            \
  SBAR();

template <int EPI>
__global__ __launch_bounds__(512, 2)
void gemm256(const _Float16* __restrict__ A, const _Float16* __restrict__ Bmat,
             long aStride, long bStride, long oStride,
             int M, int N, int K,
             void* __restrict__ outp,
             const float* __restrict__ bias,
             const float* __restrict__ addmat,
             const float* __restrict__ extra) {
  __shared__ __attribute__((aligned(16))) _Float16 smem[65536];  // 128 KB

  const int t = threadIdx.x;
  const int lane = t & 63;
  const int wid = t >> 6;
  const int wm = wid >> 2, wn = wid & 3;
  const int z = blockIdx.z;
  const int lo = lane & 15, hi = lane >> 4;
  const int slotx = hi ^ ((lo >> 1) & 3);
  const int srck = 8 * ((t & 3) ^ ((t >> 3) & 3));
  const int nt = K >> 6;

  // XCD-aware bijective swizzle (nwg % 8 == 0 for all our grids)
  const int fblk = blockIdx.x + blockIdx.y * gridDim.x;
  const int q = (gridDim.x * gridDim.y) >> 3;
  const int wg = (fblk & 7) * q + (fblk >> 3);
  const long rowBase = (long)(wg / (int)gridDim.x) * 256;
  const long colBase = (long)(wg % (int)gridDim.x) * 256;

  const _Float16* Ag = A + (size_t)z * aStride + rowBase * K;
  const _Float16* Bg = Bmat + (size_t)z * bStride + colBase * K;

  f32x4 acc[8][4] = {};

  // prologue: Ak0(0) Bk0(0) Ak1(0) Bk1(0) Ak0(1); allow newest 6 in flight
  STAGE_(0, 0, 0); STAGE_(1, 0, 0); STAGE_(0, 1, 0); STAGE_(1, 1, 0); STAGE_(0, 0, 1);
  VMCNT(6);
  SBAR();

  for (int I = 0; I < (nt >> 1); ++I) {
    const int u = 2 * I;
    PHASE_(0, 0, 0, 1, 0, u + 1, VMCNT(4))
    PHASE_(0, 1, 0, 0, 1, u + 1, (void)0)
    PHASE_(1, 0, 0, 1, 1, u + 1, (void)0)
    PHASE_(1, 1, 0, 0, 0, u + 2, VMCNT(6))
    PHASE_(0, 0, 1, 1, 0, u + 2, VMCNT(4))
    PHASE_(0, 1, 1, 0, 1, u + 2, (void)0)
    PHASE_(1, 0, 1, 1, 1, u + 2, (void)0)
    PHASE_(1, 1, 1, 0, 0, u + 3, VMCNT(6))
  }

  VMCNT(0);
  asm volatile("s_waitcnt lgkmcnt(0)" ::: "memory");
  __syncthreads();

  // ---- vectorized epilogue: per-wave LDS transpose to row-major 16-col chunks
  constexpr int EPS = 68;
  const int fr = lane & 15;
  const int fq = (lane >> 4) * 4;
  const int er = lane >> 2;
  const int ec = (lane & 3) * 16;
  const long gc0 = colBase + wn * 64 + ec;
  float* ep = (float*)smem + wid * (16 * EPS);

  f32x4 biasv[4], maskv[4], av[4];
  float sc = 0.f;
  if constexpr (EPI == 1 || EPI == 4) {
#pragma unroll
    for (int i = 0; i < 4; ++i) biasv[i] = *(const f32x4*)&bias[gc0 + i * 4];
    const long gr0 = rowBase + wm * 128 + er;
#pragma unroll
    for (int i = 0; i < 4; ++i) av[i] = *(const f32x4*)&addmat[gr0 * N + gc0 + i * 4];
  }
  if constexpr (EPI == 2) {
#pragma unroll
    for (int i = 0; i < 4; ++i) maskv[i] = *(const f32x4*)&extra[(size_t)z * N + gc0 + i * 4];
  }
  if constexpr (EPI == 3) sc = extra[z];

#pragma unroll
  for (int mf = 0; mf < 8; ++mf) {
#pragma unroll
    for (int n = 0; n < 4; ++n)
#pragma unroll
      for (int j = 0; j < 4; ++j)
        ep[(fq + j) * EPS + n * 16 + fr] = acc[mf][n][j];
    __syncthreads();
    const long gr = rowBase + wm * 128 + mf * 16 + er;
    f32x4 r[4];
#pragma unroll
    for (int i = 0; i < 4; ++i) r[i] = *(const f32x4*)&ep[er * EPS + ec + i * 4];
    f32x4 a_cur[4];
    if constexpr (EPI == 1 || EPI == 4) {
#pragma unroll
      for (int i = 0; i < 4; ++i) a_cur[i] = av[i];
      if (mf < 7) {
        const long grn = gr + 16;
#pragma unroll
        for (int i = 0; i < 4; ++i) av[i] = *(const f32x4*)&addmat[grn * N + gc0 + i * 4];
      }
    }
    if constexpr (EPI == 1) {
      _Float16* o = (_Float16*)outp + gr * N + gc0;
#pragma unroll
      for (int g = 0; g < 2; ++g) {
        f32x4 v0 = (r[2 * g] + biasv[2 * g] + a_cur[2 * g]) * SCALE_F;
        f32x4 v1 = (r[2 * g + 1] + biasv[2 * g + 1] + a_cur[2 * g + 1]) * SCALE_F;
        f16x8 h;
        h[0]=(_Float16)v0[0]; h[1]=(_Float16)v0[1]; h[2]=(_Float16)v0[2]; h[3]=(_Float16)v0[3];
        h[4]=(_Float16)v1[0]; h[5]=(_Float16)v1[1]; h[6]=(_Float16)v1[2]; h[7]=(_Float16)v1[3];
        *(f16x8*)(o + g * 8) = h;
      }
    } else if constexpr (EPI == 2) {
      float* o = (float*)outp + (size_t)z * oStride + gr * N + gc0;
#pragma unroll
      for (int i = 0; i < 4; ++i) *(f32x4*)(o + i * 4) = r[i] + maskv[i];
    } else if constexpr (EPI == 3) {
      _Float16* o = (_Float16*)outp + (size_t)z * oStride + gr * N + gc0;
#pragma unroll
      for (int g = 0; g < 2; ++g) {
        f32x4 v0 = r[2 * g] * sc;
        f32x4 v1 = r[2 * g + 1] * sc;
        f16x8 h;
        h[0]=(_Float16)v0[0]; h[1]=(_Float16)v0[1]; h[2]=(_Float16)v0[2]; h[3]=(_Float16)v0[3];
        h[4]=(_Float16)v1[0]; h[5]=(_Float16)v1[1]; h[6]=(_Float16)v1[2]; h[7]=(_Float16)v1[3];
        *(f16x8*)(o + g * 8) = h;
      }
    } else {
      float* o = (float*)outp + gr * N + gc0;
#pragma unroll
      for (int i = 0; i < 4; ++i)
        *(f32x4*)(o + i * 4) = (r[i] + biasv[i] + a_cur[i]) * SCALE_F;
    }
    __syncthreads();
  }
}

// -------------------------------------------------------------------- softmax
__global__ __launch_bounds__(256) void softmax_k(float* __restrict__ attn,
                                                 _Float16* __restrict__ attn16) {
  const size_t row = blockIdx.x;
  float* p = attn + row * SS;
  const int t = threadIdx.x;
  f32x4 v = *(const f32x4*)(p + t * 4);
  __shared__ float red[8];
  float m = fmaxf(fmaxf(v[0], v[1]), fmaxf(v[2], v[3]));
#pragma unroll
  for (int o = 32; o; o >>= 1) m = fmaxf(m, __shfl_xor(m, o));
  if (!(t & 63)) red[t >> 6] = m;
  __syncthreads();
  m = fmaxf(fmaxf(red[0], red[1]), fmaxf(red[2], red[3]));
  f32x4 e;
  e[0] = __expf(v[0] - m); e[1] = __expf(v[1] - m);
  e[2] = __expf(v[2] - m); e[3] = __expf(v[3] - m);
  float s = e[0] + e[1] + e[2] + e[3];
#pragma unroll
  for (int o = 32; o; o >>= 1) s += __shfl_xor(s, o);
  if (!(t & 63)) red[4 + (t >> 6)] = s;
  __syncthreads();
  s = red[4] + red[5] + red[6] + red[7];
  const float inv = 1.0f / s;
  f32x4 o4; o4[0]=e[0]*inv; o4[1]=e[1]*inv; o4[2]=e[2]*inv; o4[3]=e[3]*inv;
  *(f32x4*)(p + t * 4) = o4;
  f16x4 h; h[0]=(_Float16)o4[0]; h[1]=(_Float16)o4[1];
  h[2]=(_Float16)o4[2]; h[3]=(_Float16)o4[3];
  *(f16x4*)(attn16 + row * SS + t * 4) = h;
}

// -------------------------------------------------------------------- launch
extern "C" void kernel_launch(void* const* d_in, const int* in_sizes, int n_in,
                              void* d_out, int out_size, void* d_ws, size_t ws_size,
                              hipStream_t stream) {
  const float* x     = (const float*)d_in[0];
  const float* te    = (const float*)d_in[1];
  const float* keys  = (const float*)d_in[2];
  const float* vals  = (const float*)d_in[3];
  const void*  mask  = d_in[4];
  const float* w_in  = (const float*)d_in[5];
  const float* b_in  = (const float*)d_in[6];
  const float* w_out = (const float*)d_in[7];
  const float* b_out = (const float*)d_in[8];

  char* ws = (char*)d_ws;
  const size_t MB32 = 33554432;
  _Float16* buf0   = (_Float16*)(ws);
  _Float16* buf1   = (_Float16*)(ws + MB32);
  _Float16* keysT  = (_Float16*)(ws + 2 * MB32);
  _Float16* valsT  = (_Float16*)(ws + 3 * MB32);
  _Float16* win16  = (_Float16*)(ws + 4 * MB32);
  _Float16* wout16 = (_Float16*)(ws + 4 * MB32 + 2097152);
  float*    maskneg= (float*)   (ws + 4 * MB32 + 2 * 2097152);
  float*    sscale = (float*)   (ws + 4 * MB32 + 2 * 2097152 + 65536);

  float* out_main = (float*)d_out;
  float* attn_out = (float*)d_out + (size_t)BB * TT * CC;

  cvt_f16<<<dim3(16777216 / 2048), 256, 0, stream>>>(x, buf0, 16777216);
  cvt_f16<<<dim3(1048576 / 2048), 256, 0, stream>>>(w_in, win16, 1048576);
  cvt_f16<<<dim3(1048576 / 2048), 256, 0, stream>>>(w_out, wout16, 1048576);
  transpose_cvt<<<dim3(SS / 64, EE / 64, BB), 256, 0, stream>>>(keys, keysT, EE, SS);
  transpose_cvt<<<dim3(EE / 64, SS / 64, BB), 256, 0, stream>>>(vals, valsT, SS, EE);
  mask_prep<<<dim3(BB), 256, 0, stream>>>((const unsigned char*)mask, maskneg, sscale);

  gemm256<1><<<dim3(EE / 256, (BB * TT) / 256, 1), 512, 0, stream>>>(
      buf0, win16, 0, 0, 0, BB * TT, EE, CC, buf1, b_in, te, nullptr);
  gemm256<2><<<dim3(SS / 256, TT / 256, BB), 512, 0, stream>>>(
      buf1, keysT, (long)TT * EE, (long)SS * EE, (long)TT * SS,
      TT, SS, EE, attn_out, nullptr, nullptr, maskneg);
  softmax_k<<<dim3(BB * TT), 256, 0, stream>>>(attn_out, buf1);
  gemm256<3><<<dim3(EE / 256, TT / 256, BB), 512, 0, stream>>>(
      buf1, valsT, (long)TT * SS, (long)EE * SS, (long)TT * EE,
      TT, EE, SS, buf0, nullptr, nullptr, sscale);
  gemm256<4><<<dim3(CC / 256, (BB * TT) / 256, 1), 512, 0, stream>>>(
      buf0, wout16, 0, 0, 0, BB * TT, CC, EE, out_main, b_out, x, nullptr);
}